// Round 8
// baseline (2839.811 us; speedup 1.0000x reference)
//
#include <hip/hip_runtime.h>
#include <hip/hip_bf16.h>

#define T_ 2048
#define B_ 1024
#define H_ 256
#define I_ 8
#define A_ 8
#define DT_ 0.1f
#define EPS_ 1e-5f
#define LSTR 296  // bf16 elems per h_lds row
#define CH 32     // x-staging chunk (timesteps)
#define RB 8      // real batch rows per block (2 groups of 4)

typedef __attribute__((ext_vector_type(8))) short bf16x8;
typedef __attribute__((ext_vector_type(4))) float f32x4;

#if __has_builtin(__builtin_amdgcn_cvt_pk_bf16_f32)
typedef __attribute__((ext_vector_type(2))) __bf16 bf16x2;
__device__ __forceinline__ int pk2bf(float a, float b) {
    bf16x2 r = __builtin_amdgcn_cvt_pk_bf16_f32(a, b);
    return __builtin_bit_cast(int, r);
}
#else
__device__ __forceinline__ short f2bf1(float f) {
    unsigned u = __builtin_bit_cast(unsigned, f);
    u += 0x7fffu + ((u >> 16) & 1u);   // RNE
    return (short)(u >> 16);
}
__device__ __forceinline__ int pk2bf(float a, float b) {
    return (int)(unsigned short)f2bf1(a) | ((int)f2bf1(b) << 16);
}
#endif

__launch_bounds__(256, 1)
__global__ void liquid_kernel(const float* __restrict__ x,
                              const float* __restrict__ W_in,
                              const float* __restrict__ b_in,
                              const float* __restrict__ tau_param,
                              const float* __restrict__ W_rec,
                              const float* __restrict__ g1,
                              const float* __restrict__ beta1,
                              const float* __restrict__ g2,
                              const float* __restrict__ beta2,
                              const float* __restrict__ head_w,
                              const float* __restrict__ head_b,
                              float* __restrict__ out) {
    __shared__ short  h_lds[RB * LSTR];          // h_t (bf16), 8 rows
    __shared__ short  xstage[2][CH][RB][8];      // x chunks (bf16)
    __shared__ alignas(16) int zero16[4];        // zero B-frag for quads 1-3 at ks=8
    __shared__ alignas(16) float2 redt[RB][10];  // LN partials [row][wave(4)+pad]
    __shared__ float  hw[H_ * A_];               // head_w staging
    __shared__ float  outp[4][RB][A_];           // epilogue head partials

    const int tid  = threadIdx.x;
    const int w    = tid >> 6;    // wave 0..3 -> owns s-cols [w*64, w*64+64)
    const int lane = tid & 63;
    const int quad = lane >> 4;
    const int l15  = lane & 15;
    const int q2   = l15 >> 2;    // which mt-tile this lane's tail handles
    const int rr   = l15 & 3;     // row within group (4-way aliased copies)
    const int r0   = blockIdx.x * RB;

    for (int i = tid; i < RB * LSTR; i += 256) h_lds[i] = 0;
    if (tid < 4) zero16[tid] = 0;

    // ---- per-lane params ----
    f32x4 pbin[4];                               // C-seeds, all 4 mt tiles
    float p_g1s[4], p_b1s[4], p_decay[4];        // for owned cols (mt = q2)
#pragma unroll
    for (int mt = 0; mt < 4; ++mt)
#pragma unroll
        for (int r = 0; r < 4; ++r) pbin[mt][r] = b_in[w * 64 + mt * 16 + quad * 4 + r];
#pragma unroll
    for (int r = 0; r < 4; ++r) {
        int c = w * 64 + q2 * 16 + quad * 4 + r;
        p_g1s[r] = g1[c] * 2.885390082f;         // fold tanh's 2/ln2 scale
        p_b1s[r] = beta1[c] * 2.885390082f;
        float tp = tau_param[c];
        float sp = (tp > 20.f) ? tp : log1pf(expf(tp));  // softplus
        p_decay[r] = 1.0f - DT_ / sp;
    }

    // ---- A fragments (4 mt x 9 ks = 144 VGPRs, resident) ----
    bf16x8 afrag[4][9];
#pragma unroll
    for (int mt = 0; mt < 4; ++mt) {
        int cA = w * 64 + mt * 16 + l15;
#pragma unroll
        for (int ks = 0; ks < 9; ++ks) {
            bf16x8 f;
#pragma unroll
            for (int j = 0; j < 8; ++j) {
                int kg = ks * 32 + quad * 8 + j;
                float v;
                if (kg < 256)      v = W_rec[kg * H_ + cA];
                else if (kg < 264) v = W_in[(kg - 256) * H_ + cA];
                else               v = 0.f;
                f[j] = (short)pk2bf(v, v);
            }
            afrag[mt][ks] = f;
        }
    }

    // ---- x chunk loader: thread owns row tid>>5, 2 float4/chunk ----
    const int xrow = tid >> 5, xl = tid & 31;
    const float* xrbase = x + (size_t)(r0 + xrow) * T_ * I_;
    float4 xr[2];
#pragma unroll
    for (int j = 0; j < 2; ++j) xr[j] = ((const float4*)xrbase)[xl + 32 * j];
#pragma unroll
    for (int j = 0; j < 2; ++j) {
        int f4 = xl + 32 * j;                    // 0..63
        int tl = f4 >> 1, i0 = (f4 & 1) * 4;
        int2 pk = make_int2(pk2bf(xr[j].x, xr[j].y), pk2bf(xr[j].z, xr[j].w));
        *reinterpret_cast<int2*>(&xstage[0][tl][xrow][i0]) = pk;
    }
#pragma unroll
    for (int j = 0; j < 2; ++j) xr[j] = ((const float4*)(xrbase + (size_t)CH * I_))[xl + 32 * j];

    float hA[4], hB[4];
#pragma unroll
    for (int s = 0; s < 4; ++s) { hA[s] = 0.f; hB[s] = 0.f; }

    const short* hrowA = &h_lds[rr * LSTR + quad * 8];        // group A rows 0-3
    const short* hrowB = &h_lds[(4 + rr) * LSTR + quad * 8];  // group B rows 4-7

    for (int t = 0; t < T_; ++t) {
        const int tc  = t & (CH - 1);
        const int c   = t >> 5;
        const int buf = c & 1;

        __syncthreads();  // barrier #1: h_t visible

        if (tc == 16) {
#pragma unroll
            for (int j = 0; j < 2; ++j) {
                int f4 = xl + 32 * j;
                int tl = f4 >> 1, i0 = (f4 & 1) * 4;
                int2 pk = make_int2(pk2bf(xr[j].x, xr[j].y), pk2bf(xr[j].z, xr[j].w));
                *reinterpret_cast<int2*>(&xstage[buf ^ 1][tl][xrow][i0]) = pk;
            }
        }
        if (tc == 18) {
            int cc = c + 2; if (cc > (T_ / CH) - 1) cc = (T_ / CH) - 1;
#pragma unroll
            for (int j = 0; j < 2; ++j)
                xr[j] = ((const float4*)(xrbase + (size_t)cc * CH * I_))[xl + 32 * j];
        }

        // ---- dual-group GEMM: 2 independent chains x 4 mt, interleaved ----
        const short* xbA = (quad == 0) ? &xstage[buf][tc][rr][0]     : (const short*)zero16;
        const short* xbB = (quad == 0) ? &xstage[buf][tc][4 + rr][0] : (const short*)zero16;
        f32x4 accA[4], accB[4];
        {
            bf16x8 bA = *reinterpret_cast<const bf16x8*>(hrowA);
            bf16x8 bB = *reinterpret_cast<const bf16x8*>(hrowB);
#pragma unroll
            for (int mt = 0; mt < 4; ++mt) {
                accA[mt] = __builtin_amdgcn_mfma_f32_16x16x32_bf16(afrag[mt][0], bA, pbin[mt], 0, 0, 0);
                accB[mt] = __builtin_amdgcn_mfma_f32_16x16x32_bf16(afrag[mt][0], bB, pbin[mt], 0, 0, 0);
            }
        }
#pragma unroll
        for (int ks = 1; ks < 8; ++ks) {
            bf16x8 bA = *reinterpret_cast<const bf16x8*>(hrowA + ks * 32);
            bf16x8 bB = *reinterpret_cast<const bf16x8*>(hrowB + ks * 32);
#pragma unroll
            for (int mt = 0; mt < 4; ++mt) {
                accA[mt] = __builtin_amdgcn_mfma_f32_16x16x32_bf16(afrag[mt][ks], bA, accA[mt], 0, 0, 0);
                accB[mt] = __builtin_amdgcn_mfma_f32_16x16x32_bf16(afrag[mt][ks], bB, accB[mt], 0, 0, 0);
            }
        }
        {
            bf16x8 bA = *reinterpret_cast<const bf16x8*>(xbA);
            bf16x8 bB = *reinterpret_cast<const bf16x8*>(xbB);
#pragma unroll
            for (int mt = 0; mt < 4; ++mt) {
                accA[mt] = __builtin_amdgcn_mfma_f32_16x16x32_bf16(afrag[mt][8], bA, accA[mt], 0, 0, 0);
                accB[mt] = __builtin_amdgcn_mfma_f32_16x16x32_bf16(afrag[mt][8], bB, accB[mt], 0, 0, 0);
            }
        }

        // ---- LN partials: 16-val in-lane fold + 2 shfl hops, both groups ----
        float SA = 0.f, QA = 0.f, SB = 0.f, QB = 0.f;
#pragma unroll
        for (int mt = 0; mt < 4; ++mt) {
            SA += (accA[mt][0] + accA[mt][1]) + (accA[mt][2] + accA[mt][3]);
            QA += fmaf(accA[mt][0], accA[mt][0], fmaf(accA[mt][1], accA[mt][1],
                  fmaf(accA[mt][2], accA[mt][2], accA[mt][3] * accA[mt][3])));
            SB += (accB[mt][0] + accB[mt][1]) + (accB[mt][2] + accB[mt][3]);
            QB += fmaf(accB[mt][0], accB[mt][0], fmaf(accB[mt][1], accB[mt][1],
                  fmaf(accB[mt][2], accB[mt][2], accB[mt][3] * accB[mt][3])));
        }
        SA += __shfl_xor(SA, 16, 64);  QA += __shfl_xor(QA, 16, 64);
        SB += __shfl_xor(SB, 16, 64);  QB += __shfl_xor(QB, 16, 64);
        SA += __shfl_xor(SA, 32, 64);  QA += __shfl_xor(QA, 32, 64);
        SB += __shfl_xor(SB, 32, 64);  QB += __shfl_xor(QB, 32, 64);
        if (quad == 0 && q2 == 0) {
            redt[rr][w]     = make_float2(SA, QA);
            redt[4 + rr][w] = make_float2(SB, QB);
        }

        __syncthreads();  // barrier #2: partials visible

        // ---- final stats (broadcast reads), both groups ----
        const float4* ra = reinterpret_cast<const float4*>(&redt[rr][0]);
        const float4* rb = reinterpret_cast<const float4*>(&redt[4 + rr][0]);
        float4 a0 = ra[0], a1 = ra[1], b0 = rb[0], b1 = rb[1];
        float StA = (a0.x + a0.z) + (a1.x + a1.z), QtA = (a0.y + a0.w) + (a1.y + a1.w);
        float StB = (b0.x + b0.z) + (b1.x + b1.z), QtB = (b0.y + b0.w) + (b1.y + b1.w);
        float muA = StA * (1.f / 256.f), muB = StB * (1.f / 256.f);
        float rsA = __builtin_amdgcn_rsqf(fmaf(QtA, 1.f / 256.f, -muA * muA) + EPS_);
        float rsB = __builtin_amdgcn_rsqf(fmaf(QtB, 1.f / 256.f, -muB * muB) + EPS_);
        float nmA = -muA * rsA, nmB = -muB * rsB;

        // ---- extract this lane's mt (= q2) tile values ----
        bool s0 = (q2 & 1), s1 = (q2 >> 1);
        f32x4 tA0 = s0 ? accA[1] : accA[0], tA1 = s0 ? accA[3] : accA[2];
        f32x4 vA  = s1 ? tA1 : tA0;
        f32x4 tB0 = s0 ? accB[1] : accB[0], tB1 = s0 ? accB[3] : accB[2];
        f32x4 vB  = s1 ? tB1 : tB0;

        // ---- tanh + state update, both groups (4 vals each) ----
#pragma unroll
        for (int s = 0; s < 4; ++s) {
            float zA = fmaf(fmaf(vA[s], rsA, nmA), p_g1s[s], p_b1s[s]);
            float zB = fmaf(fmaf(vB[s], rsB, nmB), p_g1s[s], p_b1s[s]);
            float eA = __builtin_amdgcn_exp2f(zA);
            float eB = __builtin_amdgcn_exp2f(zB);
            float cA_ = __builtin_amdgcn_rcpf(eA + 1.f);
            float cB_ = __builtin_amdgcn_rcpf(eB + 1.f);
            float fA = fmaf(cA_, -2.f * DT_, DT_);
            float fB = fmaf(cB_, -2.f * DT_, DT_);
            hA[s] = __builtin_amdgcn_fmed3f(fmaf(hA[s], p_decay[s], fA), -10.f, 10.f);
            hB[s] = __builtin_amdgcn_fmed3f(fmaf(hB[s], p_decay[s], fB), -10.f, 10.f);
        }
        {
            int2 pA = make_int2(pk2bf(hA[0], hA[1]), pk2bf(hA[2], hA[3]));
            int2 pB = make_int2(pk2bf(hB[0], hB[1]), pk2bf(hB[2], hB[3]));
            int cbase = w * 64 + q2 * 16 + quad * 4;
            *reinterpret_cast<int2*>(&h_lds[rr * LSTR + cbase])       = pA;
            *reinterpret_cast<int2*>(&h_lds[(4 + rr) * LSTR + cbase]) = pB;
        }
    }

    // ---- epilogue: out = LN(h_T; g2,b2) @ head_w + head_b ----
    for (int i = tid; i < H_ * A_; i += 256) hw[i] = head_w[i];
    __syncthreads();

    float SA = (hA[0] + hA[1]) + (hA[2] + hA[3]);
    float QA = fmaf(hA[0], hA[0], fmaf(hA[1], hA[1], fmaf(hA[2], hA[2], hA[3] * hA[3])));
    float SB = (hB[0] + hB[1]) + (hB[2] + hB[3]);
    float QB = fmaf(hB[0], hB[0], fmaf(hB[1], hB[1], fmaf(hB[2], hB[2], hB[3] * hB[3])));
#pragma unroll
    for (int d = 4; d <= 32; d <<= 1) {
        SA += __shfl_xor(SA, d, 64);  QA += __shfl_xor(QA, d, 64);
        SB += __shfl_xor(SB, d, 64);  QB += __shfl_xor(QB, d, 64);
    }
    if (quad == 0 && q2 == 0) {
        redt[rr][w]     = make_float2(SA, QA);
        redt[4 + rr][w] = make_float2(SB, QB);
    }
    __syncthreads();
    const float4* ra = reinterpret_cast<const float4*>(&redt[rr][0]);
    const float4* rb = reinterpret_cast<const float4*>(&redt[4 + rr][0]);
    float4 a0 = ra[0], a1 = ra[1], b0 = rb[0], b1 = rb[1];
    float StA = (a0.x + a0.z) + (a1.x + a1.z), QtA = (a0.y + a0.w) + (a1.y + a1.w);
    float StB = (b0.x + b0.z) + (b1.x + b1.z), QtB = (b0.y + b0.w) + (b1.y + b1.w);
    float muA = StA * (1.f / 256.f), muB = StB * (1.f / 256.f);
    float rsA = __builtin_amdgcn_rsqf(fmaf(QtA, 1.f / 256.f, -muA * muA) + EPS_);
    float rsB = __builtin_amdgcn_rsqf(fmaf(QtB, 1.f / 256.f, -muB * muB) + EPS_);

    float paA[8], paB[8];
#pragma unroll
    for (int a = 0; a < 8; ++a) { paA[a] = 0.f; paB[a] = 0.f; }
#pragma unroll
    for (int s = 0; s < 4; ++s) {
        int cc = w * 64 + q2 * 16 + quad * 4 + s;
        float lA = (hA[s] - muA) * rsA * g2[cc] + beta2[cc];
        float lB = (hB[s] - muB) * rsB * g2[cc] + beta2[cc];
        float4 w0 = *reinterpret_cast<const float4*>(&hw[cc * 8]);
        float4 w1 = *reinterpret_cast<const float4*>(&hw[cc * 8 + 4]);
        paA[0] += lA * w0.x; paA[1] += lA * w0.y; paA[2] += lA * w0.z; paA[3] += lA * w0.w;
        paA[4] += lA * w1.x; paA[5] += lA * w1.y; paA[6] += lA * w1.z; paA[7] += lA * w1.w;
        paB[0] += lB * w0.x; paB[1] += lB * w0.y; paB[2] += lB * w0.z; paB[3] += lB * w0.w;
        paB[4] += lB * w1.x; paB[5] += lB * w1.y; paB[6] += lB * w1.z; paB[7] += lB * w1.w;
    }
#pragma unroll
    for (int a = 0; a < 8; ++a)
#pragma unroll
        for (int d = 4; d <= 32; d <<= 1) {
            paA[a] += __shfl_xor(paA[a], d, 64);
            paB[a] += __shfl_xor(paB[a], d, 64);
        }
    if (quad == 0 && q2 == 0) {
#pragma unroll
        for (int a = 0; a < 8; ++a) {
            outp[w][rr][a]     = paA[a];
            outp[w][4 + rr][a] = paB[a];
        }
    }
    __syncthreads();
    if (tid < RB * A_) {
        int r = tid >> 3, a = tid & 7;
        float s = head_b[a];
#pragma unroll
        for (int ww = 0; ww < 4; ++ww) s += outp[ww][r][a];
        out[(size_t)(r0 + r) * A_ + a] = s;
    }
}

extern "C" void kernel_launch(void* const* d_in, const int* in_sizes, int n_in,
                              void* d_out, int out_size, void* d_ws, size_t ws_size,
                              hipStream_t stream) {
    const float* x         = (const float*)d_in[0];
    const float* W_in      = (const float*)d_in[1];
    const float* b_in      = (const float*)d_in[2];
    const float* tau_param = (const float*)d_in[3];
    const float* W_rec     = (const float*)d_in[4];
    const float* g1        = (const float*)d_in[5];
    const float* beta1     = (const float*)d_in[6];
    const float* g2        = (const float*)d_in[7];
    const float* beta2     = (const float*)d_in[8];
    const float* head_w    = (const float*)d_in[9];
    const float* head_b    = (const float*)d_in[10];
    float* out = (float*)d_out;

    liquid_kernel<<<128, 256, 0, stream>>>(x, W_in, b_in, tau_param, W_rec,
                                           g1, beta1, g2, beta2, head_w, head_b, out);
}

// Round 10
// 1770.883 us; speedup vs baseline: 1.6036x; 1.6036x over previous
//
#include <hip/hip_runtime.h>
#include <hip/hip_bf16.h>

#define T_ 2048
#define B_ 1024
#define H_ 256
#define I_ 8
#define A_ 8
#define DT_ 0.1f
#define EPS_ 1e-5f
#define LSTR 304  // bf16/row: 152 dwords -> row starts banks {0,24,16,8}
#define CH 32     // x-staging chunk (timesteps)
#define RB 4      // real batch rows per block (4-way aliased in 16-slot MFMA tiles)

typedef __attribute__((ext_vector_type(8))) short bf16x8;
typedef __attribute__((ext_vector_type(4))) float f32x4;

#if __has_builtin(__builtin_amdgcn_cvt_pk_bf16_f32)
typedef __attribute__((ext_vector_type(2))) __bf16 bf16x2;
__device__ __forceinline__ int pk2bf(float a, float b) {
    bf16x2 r = __builtin_amdgcn_cvt_pk_bf16_f32(a, b);
    return __builtin_bit_cast(int, r);
}
#else
__device__ __forceinline__ short f2bf1(float f) {
    unsigned u = __builtin_bit_cast(unsigned, f);
    u += 0x7fffu + ((u >> 16) & 1u);   // RNE
    return (short)(u >> 16);
}
__device__ __forceinline__ int pk2bf(float a, float b) {
    return (int)(unsigned short)f2bf1(a) | ((int)f2bf1(b) << 16);
}
#endif

__launch_bounds__(512, 2)
__global__ void liquid_kernel(const float* __restrict__ x,
                              const float* __restrict__ W_in,
                              const float* __restrict__ b_in,
                              const float* __restrict__ tau_param,
                              const float* __restrict__ W_rec,
                              const float* __restrict__ g1,
                              const float* __restrict__ beta1,
                              const float* __restrict__ g2,
                              const float* __restrict__ beta2,
                              const float* __restrict__ head_w,
                              const float* __restrict__ head_b,
                              float* __restrict__ out) {
    __shared__ short  h_lds[RB * LSTR];          // h_t (bf16), 4 real rows
    __shared__ short  xstage[2][CH][RB][8];      // x chunks (bf16)
    __shared__ alignas(16) int zero16[4];        // zero B-frag for quads 1-3 at ks=8
    __shared__ alignas(16) float2 redt[RB][10];  // LN partials [row][wave(8)+pad]
    __shared__ float  hw[H_ * A_];               // head_w staging
    __shared__ float  outp[8][RB][A_];           // epilogue head partials

    const int tid  = threadIdx.x;
    const int w    = tid >> 6;    // wave 0..7 -> owns s-cols [w*32, w*32+32)
    const int lane = tid & 63;
    const int quad = lane >> 4;
    const int l15  = lane & 15;
    const int row  = l15 & 3;     // batch-row (4 aliased copies: l15, +4, +8, +12)
    const int cj   = l15 >> 2;    // copy index 0..3 -> tail subset
    const int mtj  = cj >> 1;     // which mt tile this lane's tail handles
    const int rbs  = (cj & 1) * 2; // which r-pair
    const int r0   = blockIdx.x * RB;

    for (int i = tid; i < RB * LSTR; i += 512) h_lds[i] = 0;
    if (tid < 4) zero16[tid] = 0;

    // ---- per-lane params ----
    f32x4 pbin0, pbin1;                      // C-seeds for mt0/mt1 (column-based)
    float p_g1s[2], p_b1s[2], p_decay[2];    // for the 2 owned tail cols
#pragma unroll
    for (int r = 0; r < 4; ++r) {
        pbin0[r] = b_in[w * 32 + quad * 4 + r];
        pbin1[r] = b_in[w * 32 + 16 + quad * 4 + r];
    }
#pragma unroll
    for (int s = 0; s < 2; ++s) {
        int c = w * 32 + mtj * 16 + quad * 4 + rbs + s;
        p_g1s[s] = g1[c] * 2.885390082f;     // fold tanh's 2/ln2 scale
        p_b1s[s] = beta1[c] * 2.885390082f;
        float tp = tau_param[c];
        float sp = (tp > 20.f) ? tp : log1pf(expf(tp));  // softplus
        p_decay[s] = 1.0f - DT_ / sp;
    }

    // ---- A fragments resident in regs: A[m=l15][k=quad*8+j] = W_ext[k][cA] ----
    // W_ext rows 0..255 = W_rec, 256..263 = W_in, 264..287 = 0
    bf16x8 afrag[2][9];
#pragma unroll
    for (int mt = 0; mt < 2; ++mt) {
        int cA = w * 32 + mt * 16 + l15;
#pragma unroll
        for (int ks = 0; ks < 9; ++ks) {
            bf16x8 f;
#pragma unroll
            for (int j = 0; j < 8; ++j) {
                int kg = ks * 32 + quad * 8 + j;
                float v;
                if (kg < 256)      v = W_rec[kg * H_ + cA];
                else if (kg < 264) v = W_in[(kg - 256) * H_ + cA];
                else               v = 0.f;
                f[j] = (short)pk2bf(v, v);
            }
            afrag[mt][ks] = f;
        }
    }

    // ---- x chunk loader: threads 0..255, one float4/chunk each ----
    const int xrow = (tid >> 6) & 3, xf4 = tid & 63;     // row 0..3, f4 idx 0..63
    const int xt = xf4 >> 1, xi0 = (xf4 & 1) * 4;
    const bool xldr = (tid < 256);
    const float* xrbase = x + (size_t)(r0 + xrow) * T_ * I_;
    float4 xr;

    if (xldr) {
        xr = ((const float4*)xrbase)[xf4];               // chunk 0
        int2 pk = make_int2(pk2bf(xr.x, xr.y), pk2bf(xr.z, xr.w));
        *reinterpret_cast<int2*>(&xstage[0][xt][xrow][xi0]) = pk;
        xr = ((const float4*)(xrbase + (size_t)CH * I_))[xf4];  // chunk 1
    }

    float hreg[2];
    hreg[0] = 0.f; hreg[1] = 0.f;

    const short* hrow = &h_lds[row * LSTR + quad * 8];
    const f32x4 zacc = {0.f, 0.f, 0.f, 0.f};

    for (int t = 0; t < T_; ++t) {
        const int tc  = t & (CH - 1);
        const int c   = t >> 5;
        const int buf = c & 1;

        __syncthreads();  // barrier #1: h_t visible

        if (xldr && tc == 16) {   // convert held regs (chunk c+1) into idle buffer
            int2 pk = make_int2(pk2bf(xr.x, xr.y), pk2bf(xr.z, xr.w));
            *reinterpret_cast<int2*>(&xstage[buf ^ 1][xt][xrow][xi0]) = pk;
        }
        if (xldr && tc == 18) {   // issue loads for chunk c+2
            int cc = c + 2; if (cc > (T_ / CH) - 1) cc = (T_ / CH) - 1;
            xr = ((const float4*)(xrbase + (size_t)cc * CH * I_))[xf4];
        }

        // ---- GEMM: 4 chains (2 mt x 2 k-halves), dep depth 5/4 ----
        const short* xb = (quad == 0) ? &xstage[buf][tc][row][0] : (const short*)zero16;
        f32x4 c0a = pbin0, c1a = pbin1, c0b = zacc, c1b = zacc;
#pragma unroll
        for (int ks = 0; ks < 4; ++ks) {
            bf16x8 bA = *reinterpret_cast<const bf16x8*>(hrow + ks * 32);
            bf16x8 bB = *reinterpret_cast<const bf16x8*>(hrow + (ks + 4) * 32);
            c0a = __builtin_amdgcn_mfma_f32_16x16x32_bf16(afrag[0][ks],     bA, c0a, 0, 0, 0);
            c1a = __builtin_amdgcn_mfma_f32_16x16x32_bf16(afrag[1][ks],     bA, c1a, 0, 0, 0);
            c0b = __builtin_amdgcn_mfma_f32_16x16x32_bf16(afrag[0][ks + 4], bB, c0b, 0, 0, 0);
            c1b = __builtin_amdgcn_mfma_f32_16x16x32_bf16(afrag[1][ks + 4], bB, c1b, 0, 0, 0);
        }
        {
            bf16x8 b8 = *reinterpret_cast<const bf16x8*>(xb);
            c0a = __builtin_amdgcn_mfma_f32_16x16x32_bf16(afrag[0][8], b8, c0a, 0, 0, 0);
            c1a = __builtin_amdgcn_mfma_f32_16x16x32_bf16(afrag[1][8], b8, c1a, 0, 0, 0);
        }
        f32x4 acc0 = c0a + c0b, acc1 = c1a + c1b;

        // ---- LN partial: in-lane fold (quad's 8 cols) + 2 shfl hops ----
        float S  = ((acc0[0] + acc0[1]) + (acc0[2] + acc0[3]))
                 + ((acc1[0] + acc1[1]) + (acc1[2] + acc1[3]));
        float SQ = fmaf(acc0[0], acc0[0], fmaf(acc0[1], acc0[1],
                   fmaf(acc0[2], acc0[2], acc0[3] * acc0[3])))
                 + fmaf(acc1[0], acc1[0], fmaf(acc1[1], acc1[1],
                   fmaf(acc1[2], acc1[2], acc1[3] * acc1[3])));
        S += __shfl_xor(S, 16, 64);  SQ += __shfl_xor(SQ, 16, 64);
        S += __shfl_xor(S, 32, 64);  SQ += __shfl_xor(SQ, 32, 64);
        if (lane < RB) redt[row][w] = make_float2(S, SQ);  // quad0, copy0 only

        __syncthreads();  // barrier #2: all wave partials in redt

        // ---- final stats: 4x ds_read_b128 (8 wave partials), broadcast rows ----
        const float4* rrow = reinterpret_cast<const float4*>(&redt[row][0]);
        float4 q0 = rrow[0], q1 = rrow[1], q2 = rrow[2], q3 = rrow[3];
        float St  = ((q0.x + q0.z) + (q1.x + q1.z)) + ((q2.x + q2.z) + (q3.x + q3.z));
        float SQt = ((q0.y + q0.w) + (q1.y + q1.w)) + ((q2.y + q2.w) + (q3.y + q3.w));
        const float mu   = St * (1.f / 256.f);
        const float var  = fmaf(SQt, 1.f / 256.f, -mu * mu);
        const float rstd = __builtin_amdgcn_rsqf(var + EPS_);
        const float nmr  = -mu * rstd;

        // ---- tail: this lane's 2 assigned values (mt=mtj, r=rbs..rbs+1) ----
        f32x4 vsrc = mtj ? acc1 : acc0;
#pragma unroll
        for (int s = 0; s < 2; ++s) {
            float v  = vsrc[rbs + s];
            float tt = fmaf(v, rstd, nmr);
            float z2 = fmaf(tt, p_g1s[s], p_b1s[s]);            // 2z/ln2
            float e  = __builtin_amdgcn_exp2f(z2);              // e^(2z)
            float rc = __builtin_amdgcn_rcpf(e + 1.f);
            float fd = fmaf(rc, -2.f * DT_, DT_);               // DT*tanh(z)
            float h  = fmaf(hreg[s], p_decay[s], fd);
            hreg[s]  = __builtin_amdgcn_fmed3f(h, -10.f, 10.f);
        }
        // pack: one ds_write_b32 per lane (2 bf16)
        *reinterpret_cast<int*>(&h_lds[row * LSTR + w * 32 + mtj * 16 + quad * 4 + rbs])
            = pk2bf(hreg[0], hreg[1]);
    }

    // ---- epilogue: out = LN(h_T; g2,b2) @ head_w + head_b ----
    for (int i = tid; i < H_ * A_; i += 512) hw[i] = head_w[i];
    __syncthreads();

    float S2  = hreg[0] + hreg[1];
    float SQ2 = fmaf(hreg[0], hreg[0], hreg[1] * hreg[1]);
    S2 += __shfl_xor(S2, 4, 64);   SQ2 += __shfl_xor(SQ2, 4, 64);
    S2 += __shfl_xor(S2, 8, 64);   SQ2 += __shfl_xor(SQ2, 8, 64);
    S2 += __shfl_xor(S2, 16, 64);  SQ2 += __shfl_xor(SQ2, 16, 64);
    S2 += __shfl_xor(S2, 32, 64);  SQ2 += __shfl_xor(SQ2, 32, 64);
    if (lane < RB) redt[row][w] = make_float2(S2, SQ2);
    __syncthreads();
    const float4* rrow = reinterpret_cast<const float4*>(&redt[row][0]);
    float4 q0 = rrow[0], q1 = rrow[1], q2 = rrow[2], q3 = rrow[3];
    float St  = ((q0.x + q0.z) + (q1.x + q1.z)) + ((q2.x + q2.z) + (q3.x + q3.z));
    float SQt = ((q0.y + q0.w) + (q1.y + q1.w)) + ((q2.y + q2.w) + (q3.y + q3.w));
    const float mu   = St * (1.f / 256.f);
    const float var  = fmaf(SQt, 1.f / 256.f, -mu * mu);
    const float rstd = __builtin_amdgcn_rsqf(var + EPS_);

    float pa[8];
#pragma unroll
    for (int a = 0; a < 8; ++a) pa[a] = 0.f;
#pragma unroll
    for (int s = 0; s < 2; ++s) {
        int cc = w * 32 + mtj * 16 + quad * 4 + rbs + s;
        float lnh = (hreg[s] - mu) * rstd * g2[cc] + beta2[cc];
        float4 w0 = *reinterpret_cast<const float4*>(&hw[cc * 8]);
        float4 w1 = *reinterpret_cast<const float4*>(&hw[cc * 8 + 4]);
        pa[0] += lnh * w0.x; pa[1] += lnh * w0.y; pa[2] += lnh * w0.z; pa[3] += lnh * w0.w;
        pa[4] += lnh * w1.x; pa[5] += lnh * w1.y; pa[6] += lnh * w1.z; pa[7] += lnh * w1.w;
    }
#pragma unroll
    for (int a = 0; a < 8; ++a) {
        pa[a] += __shfl_xor(pa[a], 4, 64);
        pa[a] += __shfl_xor(pa[a], 8, 64);
        pa[a] += __shfl_xor(pa[a], 16, 64);
        pa[a] += __shfl_xor(pa[a], 32, 64);
    }
    if (lane < RB) {
#pragma unroll
        for (int a = 0; a < 8; ++a) outp[w][row][a] = pa[a];
    }
    __syncthreads();
    if (tid < RB * A_) {
        int r = tid >> 3, a = tid & 7;
        float s = head_b[a];
#pragma unroll
        for (int ww = 0; ww < 8; ++ww) s += outp[ww][r][a];
        out[(size_t)(r0 + r) * A_ + a] = s;
    }
}

extern "C" void kernel_launch(void* const* d_in, const int* in_sizes, int n_in,
                              void* d_out, int out_size, void* d_ws, size_t ws_size,
                              hipStream_t stream) {
    const float* x         = (const float*)d_in[0];
    const float* W_in      = (const float*)d_in[1];
    const float* b_in      = (const float*)d_in[2];
    const float* tau_param = (const float*)d_in[3];
    const float* W_rec     = (const float*)d_in[4];
    const float* g1        = (const float*)d_in[5];
    const float* beta1     = (const float*)d_in[6];
    const float* g2        = (const float*)d_in[7];
    const float* beta2     = (const float*)d_in[8];
    const float* head_w    = (const float*)d_in[9];
    const float* head_b    = (const float*)d_in[10];
    float* out = (float*)d_out;

    liquid_kernel<<<256, 512, 0, stream>>>(x, W_in, b_in, tau_param, W_rec,
                                           g1, beta1, g2, beta2, head_w, head_b, out);
}